// Round 5
// baseline (166.196 us; speedup 1.0000x reference)
//
#include <hip/hip_runtime.h>
#include <hip/hip_bf16.h>

typedef __bf16 bf16x8 __attribute__((ext_vector_type(8)));
typedef __bf16 bf16x4 __attribute__((ext_vector_type(4)));
typedef float  f32x4  __attribute__((ext_vector_type(4)));

#define T_SEQ 2048
#define D_HEAD 64
#define BH_N 32
#define NT_TILES (T_SEQ / 64)        // 32
#define QT_N 32                      // 64 q-rows per block
#define IMG_BYTES 16384              // per-(bh,kt) tile image: 8KB K + 8KB V
#define SCALE_LOG2 0.18033688011112042f   // 0.125 * log2(e)

#define WS_IMG ((size_t)0)
#define WS_MB  ((size_t)16u << 20)

static __device__ __forceinline__ f32x4 mfma32(bf16x8 a, bf16x8 b, f32x4 c) {
    return __builtin_amdgcn_mfma_f32_16x16x32_bf16(a, b, c, 0, 0, 0);
}

static __device__ __forceinline__ float fast_exp2(float x) {
#if __has_builtin(__builtin_amdgcn_exp2f)
    return __builtin_amdgcn_exp2f(x);   // raw v_exp_f32; inputs bounded, no fixup needed
#else
    return exp2f(x);
#endif
}

// async global->LDS, 16B per lane. LDS dest is wave-uniform base + lane*16 (HW rule);
// the swizzle lives in the GLOBAL image layout, LDS stays linear.
static __device__ __forceinline__ void gload16(const void* g, void* l, int lane) {
#if __has_builtin(__builtin_amdgcn_global_load_lds)
    (void)lane;
    __builtin_amdgcn_global_load_lds(
        (const __attribute__((address_space(1))) void*)g,
        (__attribute__((address_space(3))) void*)l, 16, 0, 0);
#else
    *((f32x4*)l + lane) = *(const f32x4*)g;
#endif
}

// ---------------- prepass: build per-tile LDS images ----------------
// Image for (bh,kt), 16KB:
//   K half (8KB): row kr (key 0..63) x 128B; 16B chunk m = K[key][d-chunk m^(kr&7)]
//   V half (8KB): row r  (d   0..63) x 128B; 16B chunk m: u=m^(r&7), kh=u&1, g=u>>1,
//       bytes0-7 = V[32kh+4g+{0..3}][d=r], bytes8-15 = V[32kh+16+4g+{0..3}][d=r]

__global__ __launch_bounds__(256) void prep_kv(const float* __restrict__ k,
                                               const float* __restrict__ v,
                                               char* __restrict__ img) {
    __shared__ __bf16 t[64][72];
    const int bh = blockIdx.y, tt = blockIdx.x, tid = threadIdx.x;
    char* ob = img + ((size_t)bh * NT_TILES + tt) * IMG_BYTES;
    {
        const int kr = tid >> 2, qd = tid & 3, ke = kr & 7;
        const size_t base = ((size_t)bh * T_SEQ + tt * 64 + kr) * D_HEAD + qd * 16;
        const float4 a0 = *(const float4*)(k + base);
        const float4 a1 = *(const float4*)(k + base + 4);
        const float4 a2 = *(const float4*)(k + base + 8);
        const float4 a3 = *(const float4*)(k + base + 12);
        bf16x8 w0, w1;
        w0[0]=(__bf16)a0.x; w0[1]=(__bf16)a0.y; w0[2]=(__bf16)a0.z; w0[3]=(__bf16)a0.w;
        w0[4]=(__bf16)a1.x; w0[5]=(__bf16)a1.y; w0[6]=(__bf16)a1.z; w0[7]=(__bf16)a1.w;
        w1[0]=(__bf16)a2.x; w1[1]=(__bf16)a2.y; w1[2]=(__bf16)a2.z; w1[3]=(__bf16)a2.w;
        w1[4]=(__bf16)a3.x; w1[5]=(__bf16)a3.y; w1[6]=(__bf16)a3.z; w1[7]=(__bf16)a3.w;
        *(bf16x8*)(ob + kr * 128 + (((2 * qd + 0) ^ ke) << 4)) = w0;
        *(bf16x8*)(ob + kr * 128 + (((2 * qd + 1) ^ ke) << 4)) = w1;
    }
    {
        const int tr = tid >> 4, c4 = (tid & 15) * 4;
        const float* src = v + ((size_t)bh * T_SEQ + tt * 64) * D_HEAD;
#pragma unroll
        for (int p = 0; p < 4; ++p) {
            const int row = p * 16 + tr;
            const float4 f = *(const float4*)(src + row * D_HEAD + c4);
            t[c4+0][row] = (__bf16)f.x; t[c4+1][row] = (__bf16)f.y;
            t[c4+2][row] = (__bf16)f.z; t[c4+3][row] = (__bf16)f.w;
        }
        __syncthreads();
        const int d = tid >> 2;
        char* vb = ob + 8192 + d * 128;
#pragma unroll
        for (int mi = 0; mi < 2; ++mi) {
            const int m  = (tid & 3) * 2 + mi;
            const int u  = m ^ (d & 7);
            const int k0 = (u & 1) * 32 + (u >> 1) * 4;
            const bf16x4 lo = *(const bf16x4*)&t[d][k0];
            const bf16x4 hi = *(const bf16x4*)&t[d][k0 + 16];
            *(bf16x8*)(vb + m * 16) = __builtin_shufflevector(lo, hi, 0,1,2,3,4,5,6,7);
        }
    }
}

__global__ void mpack(const int* __restrict__ m, unsigned long long* __restrict__ mb) {
    const int i = blockIdx.x * 256 + threadIdx.x;
    const unsigned long long b = __ballot(m[i] != 0);
    if ((threadIdx.x & 63) == 0) mb[i >> 6] = b;
}

// ---------------- main kernel ----------------
// attn12 = attn11 with the grid/occupancy restructure: QTILE 64, 512-thr blocks, 8 waves
// = (qp = w&3 -> 16-q group, kh = w>>2 -> 32-key half). Grid 1024 -> 4 blocks/CU (LDS
// 4x33,280 <= 160K), per-wave regs ~halved (o[4]+osum vs o[2][4]+osum[2]) so
// __launch_bounds__(512,8) -> 32 waves/CU = 8/SIMD from 4 INDEPENDENT blocks. This
// attacks the measured ~70% stall fraction (latency/barrier-lockstep, no pipe >50%).
// Inner loop, image layout, mask math identical to verified attn11 minus the qs loop.

__global__ __launch_bounds__(512, 8) void attn12(
    const float* __restrict__ q, const char* __restrict__ img,
    const unsigned long long* __restrict__ mb, float* __restrict__ out)
{
    // XCD swizzle: XCD x hosts bh in [4x,4x+4), all qt. Bijective over 1024 blocks.
    const int l   = blockIdx.x;          // 0..1023
    const int bh  = ((l & 7) << 2) | ((l >> 3) & 3);
    const int qt  = l >> 5;              // 0..31 (64 q rows each)

    const int tid = threadIdx.x, wave = tid >> 6, lane = tid & 63;
    const int g = lane >> 4, ln = lane & 15;
    const int qp = wave & 3, kh = wave >> 2;

    __shared__ __align__(16) char smem[33280];
    float* Ep = (float*)smem;                // epilogue overlay: [2][64][64] f32
    float* Os = (float*)(smem + 32768);      // row sums [2][64]

    const int qw = qt * 64 + qp * 16;

    // ---- Q B-frags (log2-scaled): lane holds Q[qw+ln][kc*32+g*8+j]
    bf16x8 qf[2];
    {
        const float* qpt = q + ((size_t)bh * T_SEQ + qw + ln) * D_HEAD + g * 8;
#pragma unroll
        for (int kc = 0; kc < 2; ++kc) {
            const float4 f0 = *(const float4*)(qpt + kc * 32);
            const float4 f1 = *(const float4*)(qpt + kc * 32 + 4);
            qf[kc][0]=(__bf16)(f0.x*SCALE_LOG2); qf[kc][1]=(__bf16)(f0.y*SCALE_LOG2);
            qf[kc][2]=(__bf16)(f0.z*SCALE_LOG2); qf[kc][3]=(__bf16)(f0.w*SCALE_LOG2);
            qf[kc][4]=(__bf16)(f1.x*SCALE_LOG2); qf[kc][5]=(__bf16)(f1.y*SCALE_LOG2);
            qf[kc][6]=(__bf16)(f1.z*SCALE_LOG2); qf[kc][7]=(__bf16)(f1.w*SCALE_LOG2);
        }
    }

    f32x4 o[4];
#pragma unroll
    for (int mt = 0; mt < 4; ++mt) o[mt] = (f32x4){0.f, 0.f, 0.f, 0.f};
    f32x4 osum = (f32x4){0.f, 0.f, 0.f, 0.f};
    const bf16x8 ones8 = { (__bf16)1.0f, (__bf16)1.0f, (__bf16)1.0f, (__bf16)1.0f,
                           (__bf16)1.0f, (__bf16)1.0f, (__bf16)1.0f, (__bf16)1.0f };

    const char* ibase = img + (size_t)bh * (NT_TILES * (size_t)IMG_BYTES);
    const unsigned long long* mrow = mb + (size_t)(qw + ln) * 32;

    // ---- loop-invariant LDS read offsets (hoisted once)
    int koffs[2][2];
#pragma unroll
    for (int ntl = 0; ntl < 2; ++ntl) {
        const int row = (2 * kh + ntl) * 16 + ln;
        const int rb = row * 128 + ((g ^ (ln & 7)) << 4);
        koffs[ntl][0] = rb; koffs[ntl][1] = rb ^ 64;
    }
    int voffs[4];
#pragma unroll
    for (int mt = 0; mt < 4; ++mt)
        voffs[mt] = (mt * 16 + ln) * 128 + ((((g << 1) | kh) ^ (ln & 7)) << 4);

    char* buf0 = smem;
    char* buf1 = smem + 16384;

    auto stage = [&](int tile, char* dstbase) {
        const char* src = ibase + (size_t)tile * IMG_BYTES + wave * 2048 + lane * 16;
        char* dst = dstbase + wave * 2048;
        gload16(src, dst, lane);
        gload16(src + 1024, dst + 1024, lane);
    };

    auto compute_tile = [&](const char* KB, const char* VB, unsigned long long w0) {
        // pre-inverted keep-bit words for this wave's 32-key half, pre-shifted by g*4
        const unsigned nbs = (~(unsigned)(w0 >> (kh << 5))) >> (g * 4);

        // ---- S^T = K.Q^T; exp2 + mask -> merged P frag (key perm: j<4 grp0, j>=4 grp1)
        bf16x8 pa8;
#pragma unroll
        for (int ntl = 0; ntl < 2; ++ntl) {
            const bf16x8 a0 = *(const bf16x8*)(KB + koffs[ntl][0]);
            const bf16x8 a1 = *(const bf16x8*)(KB + koffs[ntl][1]);
            f32x4 c = (f32x4){0.f, 0.f, 0.f, 0.f};
            __builtin_amdgcn_s_setprio(1);
            c = mfma32(a0, qf[0], c);
            c = mfma32(a1, qf[1], c);
            __builtin_amdgcn_s_setprio(0);
#pragma unroll
            for (int r = 0; r < 4; ++r) {
                const float e = fast_exp2(c[r]);
                const int keep = (int)(nbs << (31 - (ntl * 16 + r))) >> 31;
                const float p = __builtin_bit_cast(float,
                    __builtin_bit_cast(unsigned, e) & (unsigned)keep);
                pa8[ntl * 4 + r] = (__bf16)p;
            }
        }

        // ---- row-sum + PV (B-frag vv covers both key groups per b128 read)
        __builtin_amdgcn_s_setprio(1);
        osum = mfma32(pa8, ones8, osum);
#pragma unroll
        for (int mt = 0; mt < 4; ++mt) {
            const bf16x8 vv = *(const bf16x8*)(VB + voffs[mt]);
            o[mt] = mfma32(pa8, vv, o[mt]);
        }
        __builtin_amdgcn_s_setprio(0);
    };

    // prologue: tile 0 -> buf0 (8 waves x 2KB each)
    stage(0, buf0);
    unsigned long long mwA = mrow[0];
    __syncthreads();

#pragma unroll 1
    for (int i = 0; i < NT_TILES / 2; ++i) {
        const int t = 2 * i;
        // half A: consume buf0 (tile t), prefetch tile t+1 -> buf1
        stage(t + 1, buf1);
        const unsigned long long mwB = mrow[t + 1];
        compute_tile(buf0, buf0 + 8192, mwA);
        __syncthreads();
        // half B: consume buf1 (tile t+1), prefetch tile t+2 -> buf0
        if (i < NT_TILES / 2 - 1) {
            stage(t + 2, buf0);
            mwA = mrow[t + 2];
        }
        compute_tile(buf1, buf1 + 8192, mwB);
        __syncthreads();
    }

    // ---- epilogue: single pass, all 8 waves write distinct (kh, qp) regions
#pragma unroll
    for (int mt = 0; mt < 4; ++mt)
#pragma unroll
        for (int r = 0; r < 4; ++r)
            Ep[(size_t)kh * 4096 + (qp * 16 + g * 4 + r) * 64 + mt * 16 + ln] = o[mt][r];
    if (ln == 0) {
#pragma unroll
        for (int r = 0; r < 4; ++r)
            Os[kh * 64 + qp * 16 + g * 4 + r] = osum[r];
    }
    __syncthreads();
    // cooperative, coalesced output: 64 rows x 64 d fp32 (512 threads -> 2 quads each)
#pragma unroll
    for (int p2 = 0; p2 < 2; ++p2) {
        const int idx = p2 * 512 + tid;
        const int row = idx >> 4, c4 = (idx & 15) * 4;
        const float sl = Os[row] + Os[64 + row];
        const float inv = (sl > 0.f) ? (1.f / sl) : 0.f;
        const float4 a  = *(const float4*)(Ep + row * 64 + c4);
        const float4 b4 = *(const float4*)(Ep + 4096 + row * 64 + c4);
        const float4 st = { (a.x + b4.x) * inv, (a.y + b4.y) * inv,
                            (a.z + b4.z) * inv, (a.w + b4.w) * inv };
        *(float4*)(out + ((size_t)bh * T_SEQ + qt * 64 + row) * D_HEAD + c4) = st;
    }
}

extern "C" void kernel_launch(void* const* d_in, const int* in_sizes, int n_in,
                              void* d_out, int out_size, void* d_ws, size_t ws_size,
                              hipStream_t stream) {
    const float* q    = (const float*)d_in[0];
    const float* k    = (const float*)d_in[1];
    const float* v    = (const float*)d_in[2];
    const int*   mask = (const int*)d_in[3];
    float*       out  = (float*)d_out;

    char* img = (char*)d_ws + WS_IMG;
    unsigned long long* mbw = (unsigned long long*)((char*)d_ws + WS_MB);

    prep_kv<<<dim3(NT_TILES, BH_N), 256, 0, stream>>>(k, v, img);
    mpack<<<(T_SEQ * T_SEQ) / 256, 256, 0, stream>>>(mask, mbw);
    attn12<<<dim3(QT_N * BH_N), 512, 0, stream>>>(q, img, mbw, out);
}

// Round 6
// 162.596 us; speedup vs baseline: 1.0221x; 1.0221x over previous
//
#include <hip/hip_runtime.h>
#include <hip/hip_bf16.h>

typedef __bf16 bf16x8 __attribute__((ext_vector_type(8)));
typedef __bf16 bf16x4 __attribute__((ext_vector_type(4)));
typedef float  f32x4  __attribute__((ext_vector_type(4)));

#define T_SEQ 2048
#define D_HEAD 64
#define BH_N 32
#define NT_TILES (T_SEQ / 64)        // 32
#define QT_N 16                      // 128 q-rows per block
#define IMG_BYTES 16384              // per-(bh,kt) tile image: 8KB K + 8KB V
#define SCALE_LOG2 0.18033688011112042f   // 0.125 * log2(e)

#define WS_IMG ((size_t)0)
#define WS_MB  ((size_t)16u << 20)

static __device__ __forceinline__ f32x4 mfma32(bf16x8 a, bf16x8 b, f32x4 c) {
    return __builtin_amdgcn_mfma_f32_16x16x32_bf16(a, b, c, 0, 0, 0);
}

static __device__ __forceinline__ float fast_exp2(float x) {
#if __has_builtin(__builtin_amdgcn_exp2f)
    return __builtin_amdgcn_exp2f(x);   // raw v_exp_f32; inputs bounded, no fixup needed
#else
    return exp2f(x);
#endif
}

// async global->LDS, 16B per lane. LDS dest is wave-uniform base + lane*16 (HW rule);
// the swizzle lives in the GLOBAL image layout, LDS stays linear.
static __device__ __forceinline__ void gload16(const void* g, void* l, int lane) {
#if __has_builtin(__builtin_amdgcn_global_load_lds)
    (void)lane;
    __builtin_amdgcn_global_load_lds(
        (const __attribute__((address_space(1))) void*)g,
        (__attribute__((address_space(3))) void*)l, 16, 0, 0);
#else
    *((f32x4*)l + lane) = *(const f32x4*)g;
#endif
}

// ---------------- prepass: build per-tile LDS images ----------------
// Image for (bh,kt), 16KB:
//   K half (8KB): row kr (key 0..63) x 128B; 16B chunk m = K[key][d-chunk m^(kr&7)]
//   V half (8KB): row r  (d   0..63) x 128B; 16B chunk m: u=m^(r&7), kh=u&1, g=u>>1,
//       bytes0-7 = V[32kh+4g+{0..3}][d=r], bytes8-15 = V[32kh+16+4g+{0..3}][d=r]

__global__ __launch_bounds__(256) void prep_kv(const float* __restrict__ k,
                                               const float* __restrict__ v,
                                               char* __restrict__ img) {
    __shared__ __bf16 t[64][72];
    const int bh = blockIdx.y, tt = blockIdx.x, tid = threadIdx.x;
    char* ob = img + ((size_t)bh * NT_TILES + tt) * IMG_BYTES;
    {
        const int kr = tid >> 2, qd = tid & 3, ke = kr & 7;
        const size_t base = ((size_t)bh * T_SEQ + tt * 64 + kr) * D_HEAD + qd * 16;
        const float4 a0 = *(const float4*)(k + base);
        const float4 a1 = *(const float4*)(k + base + 4);
        const float4 a2 = *(const float4*)(k + base + 8);
        const float4 a3 = *(const float4*)(k + base + 12);
        bf16x8 w0, w1;
        w0[0]=(__bf16)a0.x; w0[1]=(__bf16)a0.y; w0[2]=(__bf16)a0.z; w0[3]=(__bf16)a0.w;
        w0[4]=(__bf16)a1.x; w0[5]=(__bf16)a1.y; w0[6]=(__bf16)a1.z; w0[7]=(__bf16)a1.w;
        w1[0]=(__bf16)a2.x; w1[1]=(__bf16)a2.y; w1[2]=(__bf16)a2.z; w1[3]=(__bf16)a2.w;
        w1[4]=(__bf16)a3.x; w1[5]=(__bf16)a3.y; w1[6]=(__bf16)a3.z; w1[7]=(__bf16)a3.w;
        *(bf16x8*)(ob + kr * 128 + (((2 * qd + 0) ^ ke) << 4)) = w0;
        *(bf16x8*)(ob + kr * 128 + (((2 * qd + 1) ^ ke) << 4)) = w1;
    }
    {
        const int tr = tid >> 4, c4 = (tid & 15) * 4;
        const float* src = v + ((size_t)bh * T_SEQ + tt * 64) * D_HEAD;
#pragma unroll
        for (int p = 0; p < 4; ++p) {
            const int row = p * 16 + tr;
            const float4 f = *(const float4*)(src + row * D_HEAD + c4);
            t[c4+0][row] = (__bf16)f.x; t[c4+1][row] = (__bf16)f.y;
            t[c4+2][row] = (__bf16)f.z; t[c4+3][row] = (__bf16)f.w;
        }
        __syncthreads();
        const int d = tid >> 2;
        char* vb = ob + 8192 + d * 128;
#pragma unroll
        for (int mi = 0; mi < 2; ++mi) {
            const int m  = (tid & 3) * 2 + mi;
            const int u  = m ^ (d & 7);
            const int k0 = (u & 1) * 32 + (u >> 1) * 4;
            const bf16x4 lo = *(const bf16x4*)&t[d][k0];
            const bf16x4 hi = *(const bf16x4*)&t[d][k0 + 16];
            *(bf16x8*)(vb + m * 16) = __builtin_shufflevector(lo, hi, 0,1,2,3,4,5,6,7);
        }
    }
}

__global__ void mpack(const int* __restrict__ m, unsigned long long* __restrict__ mb) {
    const int i = blockIdx.x * 256 + threadIdx.x;
    const unsigned long long b = __ballot(m[i] != 0);
    if ((threadIdx.x & 63) == 0) mb[i >> 6] = b;
}

// ---------------- main kernel ----------------
// attn13 = attn11 geometry (QTILE=128, 512 thr, grid 512 -> 2 blocks/CU, 256MB L2 traffic
// = 4 TB/s, well under the ~7.2 TB/s L2 ceiling that attn9/attn12 measured) + T15
// double-pipeline: PV of tile t-1 (pure-register MFMA cluster: pa8_p x vv_p) issues
// between QK(t) and softmax(t), filling the QK->exp result-latency shadow. V-frags for
// the NEXT iteration are read from LDS *after* softmax (latency absorbed by the barrier
// + next iter's QK). Peel tile 0 / drain tile 31. Everything else verified attn11.

__global__ __launch_bounds__(512, 4) void attn13(
    const float* __restrict__ q, const char* __restrict__ img,
    const unsigned long long* __restrict__ mb, float* __restrict__ out)
{
    // XCD swizzle: linear block id -> (bh, qt) s.t. XCD x hosts bh in [4x, 4x+4), all qt.
    const int l   = blockIdx.x;          // 0..511
    const int m_  = l >> 3;              // 0..63
    const int bh  = ((l & 7) << 2) | (m_ & 3);
    const int qt  = m_ >> 2;             // 0..15 (128 q rows each)

    const int tid = threadIdx.x, wave = tid >> 6, lane = tid & 63;
    const int g = lane >> 4, ln = lane & 15;
    const int qp = wave & 3, kh = wave >> 2;

    __shared__ __align__(16) char smem[33280];
    float* Ep = (float*)smem;                // epilogue overlay: [2][64][64] f32 per pass
    float* Os = (float*)(smem + 32768);      // row sums [2][64] per pass

    const int qw = qt * 128 + qp * 32;

    // ---- Q B-frags (log2-scaled): lane n=ln holds Q[qw+qs*16+ln][kc*32+g*8+j]
    bf16x8 qf[2][2];
#pragma unroll
    for (int qs = 0; qs < 2; ++qs) {
        const float* qpt = q + ((size_t)bh * T_SEQ + qw + qs * 16 + ln) * D_HEAD + g * 8;
#pragma unroll
        for (int kc = 0; kc < 2; ++kc) {
            const float4 f0 = *(const float4*)(qpt + kc * 32);
            const float4 f1 = *(const float4*)(qpt + kc * 32 + 4);
            qf[qs][kc][0]=(__bf16)(f0.x*SCALE_LOG2); qf[qs][kc][1]=(__bf16)(f0.y*SCALE_LOG2);
            qf[qs][kc][2]=(__bf16)(f0.z*SCALE_LOG2); qf[qs][kc][3]=(__bf16)(f0.w*SCALE_LOG2);
            qf[qs][kc][4]=(__bf16)(f1.x*SCALE_LOG2); qf[qs][kc][5]=(__bf16)(f1.y*SCALE_LOG2);
            qf[qs][kc][6]=(__bf16)(f1.z*SCALE_LOG2); qf[qs][kc][7]=(__bf16)(f1.w*SCALE_LOG2);
        }
    }

    f32x4 o[2][4];
#pragma unroll
    for (int qs = 0; qs < 2; ++qs)
#pragma unroll
        for (int mt = 0; mt < 4; ++mt) o[qs][mt] = (f32x4){0.f, 0.f, 0.f, 0.f};
    f32x4 osum[2] = { (f32x4){0.f,0.f,0.f,0.f}, (f32x4){0.f,0.f,0.f,0.f} };
    const bf16x8 ones8 = { (__bf16)1.0f, (__bf16)1.0f, (__bf16)1.0f, (__bf16)1.0f,
                           (__bf16)1.0f, (__bf16)1.0f, (__bf16)1.0f, (__bf16)1.0f };

    const char* ibase = img + (size_t)bh * (NT_TILES * (size_t)IMG_BYTES);
    const unsigned long long* mrow0 = mb + (size_t)(qw + ln) * 32;
    const unsigned long long* mrow1 = mb + (size_t)(qw + 16 + ln) * 32;

    // ---- loop-invariant LDS read offsets (hoisted once)
    int koffs[2][2];
#pragma unroll
    for (int ntl = 0; ntl < 2; ++ntl) {
        const int row = (2 * kh + ntl) * 16 + ln;
        const int rb = row * 128 + ((g ^ (ln & 7)) << 4);
        koffs[ntl][0] = rb; koffs[ntl][1] = rb ^ 64;
    }
    int voffs[4];
#pragma unroll
    for (int mt = 0; mt < 4; ++mt)
        voffs[mt] = (mt * 16 + ln) * 128 + ((((g << 1) | kh) ^ (ln & 7)) << 4);

    char* buf0 = smem;
    char* buf1 = smem + 16384;

    // ---- T15 pipeline state: P-frags and V-frags of the PREVIOUS tile (registers)
    bf16x8 pa8_p[2];
    bf16x8 vv_p[4];

    auto stage = [&](int tile, char* dstbase) {
        const char* src = ibase + (size_t)tile * IMG_BYTES + wave * 2048 + lane * 16;
        char* dst = dstbase + wave * 2048;
        gload16(src, dst, lane);
        gload16(src + 1024, dst + 1024, lane);
    };

    auto QK = [&](const char* KB, f32x4 (&c)[2][2]) {
#pragma unroll
        for (int ntl = 0; ntl < 2; ++ntl) {
            const bf16x8 a0 = *(const bf16x8*)(KB + koffs[ntl][0]);
            const bf16x8 a1 = *(const bf16x8*)(KB + koffs[ntl][1]);
            __builtin_amdgcn_s_setprio(1);
#pragma unroll
            for (int qs = 0; qs < 2; ++qs) {
                f32x4 t0 = (f32x4){0.f, 0.f, 0.f, 0.f};
                t0 = mfma32(a0, qf[qs][0], t0);
                t0 = mfma32(a1, qf[qs][1], t0);
                c[ntl][qs] = t0;
            }
            __builtin_amdgcn_s_setprio(0);
        }
    };

    auto PVV = [&]() {   // PV + row-sum for the PREVIOUS tile, pure registers
        __builtin_amdgcn_s_setprio(1);
#pragma unroll
        for (int qs = 0; qs < 2; ++qs) osum[qs] = mfma32(pa8_p[qs], ones8, osum[qs]);
#pragma unroll
        for (int mt = 0; mt < 4; ++mt)
#pragma unroll
            for (int qs = 0; qs < 2; ++qs)
                o[qs][mt] = mfma32(pa8_p[qs], vv_p[mt], o[qs][mt]);
        __builtin_amdgcn_s_setprio(0);
    };

    auto SOFT = [&](const f32x4 (&c)[2][2], unsigned long long w0, unsigned long long w1) {
        const unsigned nbs0 = (~(unsigned)(w0 >> (kh << 5))) >> (g * 4);
        const unsigned nbs1 = (~(unsigned)(w1 >> (kh << 5))) >> (g * 4);
#pragma unroll
        for (int ntl = 0; ntl < 2; ++ntl)
#pragma unroll
            for (int qs = 0; qs < 2; ++qs) {
                const unsigned nbs = qs ? nbs1 : nbs0;
#pragma unroll
                for (int r = 0; r < 4; ++r) {
                    const float e = fast_exp2(c[ntl][qs][r]);
                    const int keep = (int)(nbs << (31 - (ntl * 16 + r))) >> 31;
                    const float p = __builtin_bit_cast(float,
                        __builtin_bit_cast(unsigned, e) & (unsigned)keep);
                    pa8_p[qs][ntl * 4 + r] = (__bf16)p;
                }
            }
    };

    auto VREAD = [&](const char* KB) {   // V-frags for NEXT iter's PV (read late)
        const char* VB = KB + 8192;
#pragma unroll
        for (int mt = 0; mt < 4; ++mt) vv_p[mt] = *(const bf16x8*)(VB + voffs[mt]);
    };

    // prologue: tile 0 -> buf0
    stage(0, buf0);
    __syncthreads();

    {   // peel: tile 0 (no PV yet)
        stage(1, buf1);
        const unsigned long long w0 = mrow0[0], w1 = mrow1[0];
        f32x4 c[2][2];
        QK(buf0, c);
        SOFT(c, w0, w1);
        VREAD(buf0);
        __syncthreads();
    }

#pragma unroll 1
    for (int i = 0; i < 15; ++i) {
        {   // tile 2i+1 (buf1)
            const int t = 2 * i + 1;
            stage(t + 1, buf0);
            const unsigned long long w0 = mrow0[t], w1 = mrow1[t];
            f32x4 c[2][2];
            QK(buf1, c);
            PVV();               // tile t-1
            SOFT(c, w0, w1);
            VREAD(buf1);
            __syncthreads();
        }
        {   // tile 2i+2 (buf0)
            const int t = 2 * i + 2;
            stage(t + 1, buf1);
            const unsigned long long w0 = mrow0[t], w1 = mrow1[t];
            f32x4 c[2][2];
            QK(buf0, c);
            PVV();               // tile t-1
            SOFT(c, w0, w1);
            VREAD(buf0);
            __syncthreads();
        }
    }

    {   // drain: tile 31 (buf1), no stage
        const unsigned long long w0 = mrow0[31], w1 = mrow1[31];
        f32x4 c[2][2];
        QK(buf1, c);
        PVV();                   // tile 30
        SOFT(c, w0, w1);
        VREAD(buf1);
        __syncthreads();
    }
    PVV();                       // tile 31 (registers only; smem now free)

    // ---- epilogue: two 64-row passes; kh halves combined through LDS
#pragma unroll
    for (int pass = 0; pass < 2; ++pass) {
        if ((qp >> 1) == pass) {
            const int qpl = qp & 1;
#pragma unroll
            for (int qs = 0; qs < 2; ++qs) {
#pragma unroll
                for (int mt = 0; mt < 4; ++mt)
#pragma unroll
                    for (int r = 0; r < 4; ++r)
                        Ep[(size_t)kh * 4096 + (qpl * 32 + qs * 16 + g * 4 + r) * 64 + mt * 16 + ln] = o[qs][mt][r];
                if (ln == 0) {
#pragma unroll
                    for (int r = 0; r < 4; ++r)
                        Os[kh * 64 + qpl * 32 + qs * 16 + g * 4 + r] = osum[qs][r];
                }
            }
        }
        __syncthreads();
        // cooperative, coalesced output: 64 rows x 64 d fp32 (512 threads -> 2 quads each)
#pragma unroll
        for (int p2 = 0; p2 < 2; ++p2) {
            const int idx = p2 * 512 + tid;
            const int row = idx >> 4, c4 = (idx & 15) * 4;
            const float sl = Os[row] + Os[64 + row];
            const float inv = (sl > 0.f) ? (1.f / sl) : 0.f;
            const float4 a  = *(const float4*)(Ep + row * 64 + c4);
            const float4 b4 = *(const float4*)(Ep + 4096 + row * 64 + c4);
            const float4 st = { (a.x + b4.x) * inv, (a.y + b4.y) * inv,
                                (a.z + b4.z) * inv, (a.w + b4.w) * inv };
            *(float4*)(out + ((size_t)bh * T_SEQ + qt * 128 + pass * 64 + row) * D_HEAD + c4) = st;
        }
        if (pass == 0) __syncthreads();   // Ep/Os reused by pass 1
    }
}

extern "C" void kernel_launch(void* const* d_in, const int* in_sizes, int n_in,
                              void* d_out, int out_size, void* d_ws, size_t ws_size,
                              hipStream_t stream) {
    const float* q    = (const float*)d_in[0];
    const float* k    = (const float*)d_in[1];
    const float* v    = (const float*)d_in[2];
    const int*   mask = (const int*)d_in[3];
    float*       out  = (float*)d_out;

    char* img = (char*)d_ws + WS_IMG;
    unsigned long long* mbw = (unsigned long long*)((char*)d_ws + WS_MB);

    prep_kv<<<dim3(NT_TILES, BH_N), 256, 0, stream>>>(k, v, img);
    mpack<<<(T_SEQ * T_SEQ) / 256, 256, 0, stream>>>(mask, mbw);
    attn13<<<dim3(QT_N * BH_N), 512, 0, stream>>>(q, img, mbw, out);
}

// Round 7
// 159.892 us; speedup vs baseline: 1.0394x; 1.0169x over previous
//
#include <hip/hip_runtime.h>
#include <hip/hip_bf16.h>

typedef __bf16 bf16x8 __attribute__((ext_vector_type(8)));
typedef __bf16 bf16x4 __attribute__((ext_vector_type(4)));
typedef float  f32x4  __attribute__((ext_vector_type(4)));

#define T_SEQ 2048
#define D_HEAD 64
#define BH_N 32
#define NT_TILES (T_SEQ / 64)        // 32
#define QT_N 16                      // 128 q-rows per block
#define IMG_BYTES 16384              // per-(bh,kt) tile image: 8KB K + 8KB V
#define SCALE_LOG2 0.18033688011112042f   // 0.125 * log2(e)

#define WS_IMG ((size_t)0)
#define WS_MB  ((size_t)16u << 20)

static __device__ __forceinline__ f32x4 mfma32(bf16x8 a, bf16x8 b, f32x4 c) {
    return __builtin_amdgcn_mfma_f32_16x16x32_bf16(a, b, c, 0, 0, 0);
}

static __device__ __forceinline__ float fast_exp2(float x) {
#if __has_builtin(__builtin_amdgcn_exp2f)
    return __builtin_amdgcn_exp2f(x);   // raw v_exp_f32; inputs bounded, no fixup needed
#else
    return exp2f(x);
#endif
}

// async global->LDS, 16B per lane. LDS dest is wave-uniform base + lane*16 (HW rule);
// the swizzle lives in the GLOBAL image layout, LDS stays linear.
static __device__ __forceinline__ void gload16(const void* g, void* l, int lane) {
#if __has_builtin(__builtin_amdgcn_global_load_lds)
    (void)lane;
    __builtin_amdgcn_global_load_lds(
        (const __attribute__((address_space(1))) void*)g,
        (__attribute__((address_space(3))) void*)l, 16, 0, 0);
#else
    *((f32x4*)l + lane) = *(const f32x4*)g;
#endif
}

// ---------------- prepass: build per-tile LDS images ----------------
// Image for (bh,kt), 16KB:
//   K half (8KB): row kr (key 0..63) x 128B; 16B chunk m = K[key][d-chunk m^(kr&7)]
//   V half (8KB): row r  (d   0..63) x 128B; 16B chunk m: u=m^(r&7), kh=u&1, g=u>>1,
//       bytes0-7 = V[32kh+4g+{0..3}][d=r], bytes8-15 = V[32kh+16+4g+{0..3}][d=r]

__global__ __launch_bounds__(256) void prep_kv(const float* __restrict__ k,
                                               const float* __restrict__ v,
                                               char* __restrict__ img) {
    __shared__ __bf16 t[64][72];
    const int bh = blockIdx.y, tt = blockIdx.x, tid = threadIdx.x;
    char* ob = img + ((size_t)bh * NT_TILES + tt) * IMG_BYTES;
    {
        const int kr = tid >> 2, qd = tid & 3, ke = kr & 7;
        const size_t base = ((size_t)bh * T_SEQ + tt * 64 + kr) * D_HEAD + qd * 16;
        const float4 a0 = *(const float4*)(k + base);
        const float4 a1 = *(const float4*)(k + base + 4);
        const float4 a2 = *(const float4*)(k + base + 8);
        const float4 a3 = *(const float4*)(k + base + 12);
        bf16x8 w0, w1;
        w0[0]=(__bf16)a0.x; w0[1]=(__bf16)a0.y; w0[2]=(__bf16)a0.z; w0[3]=(__bf16)a0.w;
        w0[4]=(__bf16)a1.x; w0[5]=(__bf16)a1.y; w0[6]=(__bf16)a1.z; w0[7]=(__bf16)a1.w;
        w1[0]=(__bf16)a2.x; w1[1]=(__bf16)a2.y; w1[2]=(__bf16)a2.z; w1[3]=(__bf16)a2.w;
        w1[4]=(__bf16)a3.x; w1[5]=(__bf16)a3.y; w1[6]=(__bf16)a3.z; w1[7]=(__bf16)a3.w;
        *(bf16x8*)(ob + kr * 128 + (((2 * qd + 0) ^ ke) << 4)) = w0;
        *(bf16x8*)(ob + kr * 128 + (((2 * qd + 1) ^ ke) << 4)) = w1;
    }
    {
        const int tr = tid >> 4, c4 = (tid & 15) * 4;
        const float* src = v + ((size_t)bh * T_SEQ + tt * 64) * D_HEAD;
#pragma unroll
        for (int p = 0; p < 4; ++p) {
            const int row = p * 16 + tr;
            const float4 f = *(const float4*)(src + row * D_HEAD + c4);
            t[c4+0][row] = (__bf16)f.x; t[c4+1][row] = (__bf16)f.y;
            t[c4+2][row] = (__bf16)f.z; t[c4+3][row] = (__bf16)f.w;
        }
        __syncthreads();
        const int d = tid >> 2;
        char* vb = ob + 8192 + d * 128;
#pragma unroll
        for (int mi = 0; mi < 2; ++mi) {
            const int m  = (tid & 3) * 2 + mi;
            const int u  = m ^ (d & 7);
            const int k0 = (u & 1) * 32 + (u >> 1) * 4;
            const bf16x4 lo = *(const bf16x4*)&t[d][k0];
            const bf16x4 hi = *(const bf16x4*)&t[d][k0 + 16];
            *(bf16x8*)(vb + m * 16) = __builtin_shufflevector(lo, hi, 0,1,2,3,4,5,6,7);
        }
    }
}

__global__ void mpack(const int* __restrict__ m, unsigned long long* __restrict__ mb) {
    const int i = blockIdx.x * 256 + threadIdx.x;
    const unsigned long long b = __ballot(m[i] != 0);
    if ((threadIdx.x & 63) == 0) mb[i >> 6] = b;
}

// ---------------- main kernel ----------------
// attn14 = the untested quadrant: HIGH occupancy + LOW traffic. QTILE=128 (256MB image
// traffic, 1.8x under the measured ~7.2 TB/s L2 ceiling) with 1024-thr blocks: 16 waves
// (qp = w&7 -> 16-q group, kh = w>>3 -> 32-key half), grid 512 -> 2 blocks/CU =
// 8 waves/SIMD (2x attn11) from 2 independent barrier streams. Per-wave work is attn12's
// verified shape (9 MFMA, 8 scores/lane, ~32 VGPR measured) -> fits the 64-VGPR cap of
// __launch_bounds__(1024,8) that guarantees 2-block residency. Staging: 1
// global_load_lds x 16B per wave per tile (16 waves x 1KB = 16KB image).

__global__ __launch_bounds__(1024, 8) void attn14(
    const float* __restrict__ q, const char* __restrict__ img,
    const unsigned long long* __restrict__ mb, float* __restrict__ out)
{
    // XCD swizzle: linear block id -> (bh, qt) s.t. XCD x hosts bh in [4x, 4x+4), all qt.
    const int l   = blockIdx.x;          // 0..511
    const int m_  = l >> 3;              // 0..63
    const int bh  = ((l & 7) << 2) | (m_ & 3);
    const int qt  = m_ >> 2;             // 0..15 (128 q rows each)

    const int tid = threadIdx.x, wave = tid >> 6, lane = tid & 63;
    const int g = lane >> 4, ln = lane & 15;
    const int qp = wave & 7, kh = wave >> 3;

    __shared__ __align__(16) char smem[33280];
    float* Ep = (float*)smem;                // epilogue overlay: [2][64][64] f32 per pass
    float* Os = (float*)(smem + 32768);      // row sums [2][64] per pass

    const int qw = qt * 128 + qp * 16;

    // ---- Q B-frags (log2-scaled): lane holds Q[qw+ln][kc*32+g*8+j]
    bf16x8 qf[2];
    {
        const float* qpt = q + ((size_t)bh * T_SEQ + qw + ln) * D_HEAD + g * 8;
#pragma unroll
        for (int kc = 0; kc < 2; ++kc) {
            const float4 f0 = *(const float4*)(qpt + kc * 32);
            const float4 f1 = *(const float4*)(qpt + kc * 32 + 4);
            qf[kc][0]=(__bf16)(f0.x*SCALE_LOG2); qf[kc][1]=(__bf16)(f0.y*SCALE_LOG2);
            qf[kc][2]=(__bf16)(f0.z*SCALE_LOG2); qf[kc][3]=(__bf16)(f0.w*SCALE_LOG2);
            qf[kc][4]=(__bf16)(f1.x*SCALE_LOG2); qf[kc][5]=(__bf16)(f1.y*SCALE_LOG2);
            qf[kc][6]=(__bf16)(f1.z*SCALE_LOG2); qf[kc][7]=(__bf16)(f1.w*SCALE_LOG2);
        }
    }

    f32x4 o[4];
#pragma unroll
    for (int mt = 0; mt < 4; ++mt) o[mt] = (f32x4){0.f, 0.f, 0.f, 0.f};
    f32x4 osum = (f32x4){0.f, 0.f, 0.f, 0.f};
    const bf16x8 ones8 = { (__bf16)1.0f, (__bf16)1.0f, (__bf16)1.0f, (__bf16)1.0f,
                           (__bf16)1.0f, (__bf16)1.0f, (__bf16)1.0f, (__bf16)1.0f };

    const char* ibase = img + (size_t)bh * (NT_TILES * (size_t)IMG_BYTES);
    const unsigned long long* mrow = mb + (size_t)(qw + ln) * 32;

    // ---- loop-invariant LDS read offsets (hoisted once)
    int koffs[2][2];
#pragma unroll
    for (int ntl = 0; ntl < 2; ++ntl) {
        const int row = (2 * kh + ntl) * 16 + ln;
        const int rb = row * 128 + ((g ^ (ln & 7)) << 4);
        koffs[ntl][0] = rb; koffs[ntl][1] = rb ^ 64;
    }
    int voffs[4];
#pragma unroll
    for (int mt = 0; mt < 4; ++mt)
        voffs[mt] = (mt * 16 + ln) * 128 + ((((g << 1) | kh) ^ (ln & 7)) << 4);

    char* buf0 = smem;
    char* buf1 = smem + 16384;

    auto stage = [&](int tile, char* dstbase) {
        const char* src = ibase + (size_t)tile * IMG_BYTES + wave * 1024 + lane * 16;
        gload16(src, dstbase + wave * 1024, lane);
    };

    auto compute_tile = [&](const char* KB, const char* VB, unsigned long long w0) {
        // pre-inverted keep-bit word for this wave's 32-key half, pre-shifted by g*4
        const unsigned nbs = (~(unsigned)(w0 >> (kh << 5))) >> (g * 4);

        // ---- S^T = K.Q^T; exp2 + mask -> merged P frag (key perm: j<4 grp0, j>=4 grp1)
        bf16x8 pa8;
#pragma unroll
        for (int ntl = 0; ntl < 2; ++ntl) {
            const bf16x8 a0 = *(const bf16x8*)(KB + koffs[ntl][0]);
            const bf16x8 a1 = *(const bf16x8*)(KB + koffs[ntl][1]);
            f32x4 c = (f32x4){0.f, 0.f, 0.f, 0.f};
            __builtin_amdgcn_s_setprio(1);
            c = mfma32(a0, qf[0], c);
            c = mfma32(a1, qf[1], c);
            __builtin_amdgcn_s_setprio(0);
#pragma unroll
            for (int r = 0; r < 4; ++r) {
                const float e = fast_exp2(c[r]);
                const int keep = (int)(nbs << (31 - (ntl * 16 + r))) >> 31;
                const float p = __builtin_bit_cast(float,
                    __builtin_bit_cast(unsigned, e) & (unsigned)keep);
                pa8[ntl * 4 + r] = (__bf16)p;
            }
        }

        // ---- row-sum + PV (B-frag vv covers both key groups per b128 read)
        __builtin_amdgcn_s_setprio(1);
        osum = mfma32(pa8, ones8, osum);
#pragma unroll
        for (int mt = 0; mt < 4; ++mt) {
            const bf16x8 vv = *(const bf16x8*)(VB + voffs[mt]);
            o[mt] = mfma32(pa8, vv, o[mt]);
        }
        __builtin_amdgcn_s_setprio(0);
    };

    // prologue: tile 0 -> buf0 (16 waves x 1KB each)
    stage(0, buf0);
    unsigned long long mwA = mrow[0];
    __syncthreads();

#pragma unroll 1
    for (int i = 0; i < NT_TILES / 2; ++i) {
        const int t = 2 * i;
        // half A: consume buf0 (tile t), prefetch tile t+1 -> buf1
        stage(t + 1, buf1);
        const unsigned long long mwB = mrow[t + 1];
        compute_tile(buf0, buf0 + 8192, mwA);
        __syncthreads();
        // half B: consume buf1 (tile t+1), prefetch tile t+2 -> buf0
        if (i < NT_TILES / 2 - 1) {
            stage(t + 2, buf0);
            mwA = mrow[t + 2];
        }
        compute_tile(buf1, buf1 + 8192, mwB);
        __syncthreads();
    }

    // ---- epilogue: two 64-row passes; kh halves combined through LDS
#pragma unroll
    for (int pass = 0; pass < 2; ++pass) {
        if ((qp >> 2) == pass) {
            const int qpl = qp & 3;
#pragma unroll
            for (int mt = 0; mt < 4; ++mt)
#pragma unroll
                for (int r = 0; r < 4; ++r)
                    Ep[(size_t)kh * 4096 + (qpl * 16 + g * 4 + r) * 64 + mt * 16 + ln] = o[mt][r];
            if (ln == 0) {
#pragma unroll
                for (int r = 0; r < 4; ++r)
                    Os[kh * 64 + qpl * 16 + g * 4 + r] = osum[r];
            }
        }
        __syncthreads();
        // cooperative, coalesced output: 64 rows x 64 d fp32 (1024 threads -> 1 quad each)
        {
            const int row = tid >> 4, c4 = (tid & 15) * 4;
            const float sl = Os[row] + Os[64 + row];
            const float inv = (sl > 0.f) ? (1.f / sl) : 0.f;
            const float4 a  = *(const float4*)(Ep + row * 64 + c4);
            const float4 b4 = *(const float4*)(Ep + 4096 + row * 64 + c4);
            const float4 st = { (a.x + b4.x) * inv, (a.y + b4.y) * inv,
                                (a.z + b4.z) * inv, (a.w + b4.w) * inv };
            *(float4*)(out + ((size_t)bh * T_SEQ + qt * 128 + pass * 64 + row) * D_HEAD + c4) = st;
        }
        if (pass == 0) __syncthreads();   // Ep/Os reused by pass 1
    }
}

extern "C" void kernel_launch(void* const* d_in, const int* in_sizes, int n_in,
                              void* d_out, int out_size, void* d_ws, size_t ws_size,
                              hipStream_t stream) {
    const float* q    = (const float*)d_in[0];
    const float* k    = (const float*)d_in[1];
    const float* v    = (const float*)d_in[2];
    const int*   mask = (const int*)d_in[3];
    float*       out  = (float*)d_out;

    char* img = (char*)d_ws + WS_IMG;
    unsigned long long* mbw = (unsigned long long*)((char*)d_ws + WS_MB);

    prep_kv<<<dim3(NT_TILES, BH_N), 256, 0, stream>>>(k, v, img);
    mpack<<<(T_SEQ * T_SEQ) / 256, 256, 0, stream>>>(mask, mbw);
    attn14<<<dim3(QT_N * BH_N), 1024, 0, stream>>>(q, img, mbw, out);
}

// Round 8
// 155.602 us; speedup vs baseline: 1.0681x; 1.0276x over previous
//
#include <hip/hip_runtime.h>
#include <hip/hip_bf16.h>

typedef __bf16 bf16x8 __attribute__((ext_vector_type(8)));
typedef __bf16 bf16x4 __attribute__((ext_vector_type(4)));
typedef float  f32x4  __attribute__((ext_vector_type(4)));

#define T_SEQ 2048
#define D_HEAD 64
#define BH_N 32
#define NT_TILES (T_SEQ / 64)        // 32
#define QT_N 16                      // 128 q-rows per block
#define IMG_BYTES 16384              // per-(bh,kt) tile image: 8KB K + 8KB V
#define SCALE_LOG2 0.18033688011112042f   // 0.125 * log2(e)

#define WS_IMG ((size_t)0)
#define WS_MB  ((size_t)16u << 20)

static __device__ __forceinline__ f32x4 mfma32(bf16x8 a, bf16x8 b, f32x4 c) {
    return __builtin_amdgcn_mfma_f32_16x16x32_bf16(a, b, c, 0, 0, 0);
}

static __device__ __forceinline__ float fast_exp2(float x) {
#if __has_builtin(__builtin_amdgcn_exp2f)
    return __builtin_amdgcn_exp2f(x);   // raw v_exp_f32; inputs bounded, no fixup needed
#else
    return exp2f(x);
#endif
}

// async global->LDS, 16B per lane. LDS dest is wave-uniform base + lane*16 (HW rule);
// the swizzle lives in the GLOBAL image layout, LDS stays linear.
static __device__ __forceinline__ void gload16(const void* g, void* l, int lane) {
#if __has_builtin(__builtin_amdgcn_global_load_lds)
    (void)lane;
    __builtin_amdgcn_global_load_lds(
        (const __attribute__((address_space(1))) void*)g,
        (__attribute__((address_space(3))) void*)l, 16, 0, 0);
#else
    *((f32x4*)l + lane) = *(const f32x4*)g;
#endif
}

// ---------------- prepass: build per-tile LDS images ----------------
// Image for (bh,kt), 16KB:
//   K half (8KB): row kr (key 0..63) x 128B; 16B chunk m = K[key][d-chunk m^(kr&7)]
//   V half (8KB): row r  (d   0..63) x 128B; 16B chunk m: u=m^(r&7), kh=u&1, g=u>>1,
//       bytes0-7 = V[32kh+4g+{0..3}][d=r], bytes8-15 = V[32kh+16+4g+{0..3}][d=r]

__global__ __launch_bounds__(256) void prep_kv(const float* __restrict__ k,
                                               const float* __restrict__ v,
                                               char* __restrict__ img) {
    __shared__ __bf16 t[64][72];
    const int bh = blockIdx.y, tt = blockIdx.x, tid = threadIdx.x;
    char* ob = img + ((size_t)bh * NT_TILES + tt) * IMG_BYTES;
    {
        const int kr = tid >> 2, qd = tid & 3, ke = kr & 7;
        const size_t base = ((size_t)bh * T_SEQ + tt * 64 + kr) * D_HEAD + qd * 16;
        const float4 a0 = *(const float4*)(k + base);
        const float4 a1 = *(const float4*)(k + base + 4);
        const float4 a2 = *(const float4*)(k + base + 8);
        const float4 a3 = *(const float4*)(k + base + 12);
        bf16x8 w0, w1;
        w0[0]=(__bf16)a0.x; w0[1]=(__bf16)a0.y; w0[2]=(__bf16)a0.z; w0[3]=(__bf16)a0.w;
        w0[4]=(__bf16)a1.x; w0[5]=(__bf16)a1.y; w0[6]=(__bf16)a1.z; w0[7]=(__bf16)a1.w;
        w1[0]=(__bf16)a2.x; w1[1]=(__bf16)a2.y; w1[2]=(__bf16)a2.z; w1[3]=(__bf16)a2.w;
        w1[4]=(__bf16)a3.x; w1[5]=(__bf16)a3.y; w1[6]=(__bf16)a3.z; w1[7]=(__bf16)a3.w;
        *(bf16x8*)(ob + kr * 128 + (((2 * qd + 0) ^ ke) << 4)) = w0;
        *(bf16x8*)(ob + kr * 128 + (((2 * qd + 1) ^ ke) << 4)) = w1;
    }
    {
        const int tr = tid >> 4, c4 = (tid & 15) * 4;
        const float* src = v + ((size_t)bh * T_SEQ + tt * 64) * D_HEAD;
#pragma unroll
        for (int p = 0; p < 4; ++p) {
            const int row = p * 16 + tr;
            const float4 f = *(const float4*)(src + row * D_HEAD + c4);
            t[c4+0][row] = (__bf16)f.x; t[c4+1][row] = (__bf16)f.y;
            t[c4+2][row] = (__bf16)f.z; t[c4+3][row] = (__bf16)f.w;
        }
        __syncthreads();
        const int d = tid >> 2;
        char* vb = ob + 8192 + d * 128;
#pragma unroll
        for (int mi = 0; mi < 2; ++mi) {
            const int m  = (tid & 3) * 2 + mi;
            const int u  = m ^ (d & 7);
            const int k0 = (u & 1) * 32 + (u >> 1) * 4;
            const bf16x4 lo = *(const bf16x4*)&t[d][k0];
            const bf16x4 hi = *(const bf16x4*)&t[d][k0 + 16];
            *(bf16x8*)(vb + m * 16) = __builtin_shufflevector(lo, hi, 0,1,2,3,4,5,6,7);
        }
    }
}

// mask prepass: transposed + pre-inverted + kh-pre-split keep-bit words.
// nbt[(t*2 + kh)*2048 + row] = ~bits(mask[row][t*64 + kh*32 .. +31])
// -> the kernel's per-tile mask read is 16 CONSECUTIVE u32 (1 cacheline, broadcast
//    across g-groups) instead of a 16-cacheline stride-256B gather.
__global__ void mpack(const int* __restrict__ m, unsigned* __restrict__ nbt) {
    const int i = blockIdx.x * 256 + threadIdx.x;
    const unsigned long long b = __ballot(m[i] != 0);
    if ((threadIdx.x & 63) == 0) {
        const int wi  = i >> 6;          // word index = row*32 + t
        const int row = wi >> 5;
        const int t   = wi & 31;
        nbt[(size_t)(t * 2 + 0) * 2048 + row] = ~(unsigned)b;
        nbt[(size_t)(t * 2 + 1) * 2048 + row] = ~(unsigned)(b >> 32);
    }
}

// ---------------- main kernel ----------------
// attn15 = attn11 (best measured base) + vmem-gather fix + C-init fix:
//  (1) mask words via nbt: coalesced 1-line loads, pre-inverted, pre-kh-split
//      (the old stride-256B gathers were ~16 cachelines per wave-tile, issued by every
//       wave every tile and force-drained at every __syncthreads vmcnt(0));
//  (2) persistent z4 zero-register as C-in of the first QK MFMA (kills 16 v_mov/wave-tile).
// Geometry, image layout, K-loop, epilogue identical to attn11 (verified).

__global__ __launch_bounds__(512, 4) void attn15(
    const float* __restrict__ q, const char* __restrict__ img,
    const unsigned* __restrict__ nbt, float* __restrict__ out)
{
    // XCD swizzle: linear block id -> (bh, qt) s.t. XCD x hosts bh in [4x, 4x+4), all qt.
    const int l   = blockIdx.x;          // 0..511
    const int m_  = l >> 3;              // 0..63
    const int bh  = ((l & 7) << 2) | (m_ & 3);
    const int qt  = m_ >> 2;             // 0..15 (128 q rows each)

    const int tid = threadIdx.x, wave = tid >> 6, lane = tid & 63;
    const int g = lane >> 4, ln = lane & 15;
    const int qp = wave & 3, kh = wave >> 2;
    const int g4 = g * 4;

    __shared__ __align__(16) char smem[33280];
    float* Ep = (float*)smem;                // epilogue overlay: [2][64][64] f32 per pass
    float* Os = (float*)(smem + 32768);      // row sums [2][64] per pass

    const int qw = qt * 128 + qp * 32;

    // ---- Q B-frags (log2-scaled): lane n=ln holds Q[qw+qs*16+ln][kc*32+g*8+j]
    bf16x8 qf[2][2];
#pragma unroll
    for (int qs = 0; qs < 2; ++qs) {
        const float* qpt = q + ((size_t)bh * T_SEQ + qw + qs * 16 + ln) * D_HEAD + g * 8;
#pragma unroll
        for (int kc = 0; kc < 2; ++kc) {
            const float4 f0 = *(const float4*)(qpt + kc * 32);
            const float4 f1 = *(const float4*)(qpt + kc * 32 + 4);
            qf[qs][kc][0]=(__bf16)(f0.x*SCALE_LOG2); qf[qs][kc][1]=(__bf16)(f0.y*SCALE_LOG2);
            qf[qs][kc][2]=(__bf16)(f0.z*SCALE_LOG2); qf[qs][kc][3]=(__bf16)(f0.w*SCALE_LOG2);
            qf[qs][kc][4]=(__bf16)(f1.x*SCALE_LOG2); qf[qs][kc][5]=(__bf16)(f1.y*SCALE_LOG2);
            qf[qs][kc][6]=(__bf16)(f1.z*SCALE_LOG2); qf[qs][kc][7]=(__bf16)(f1.w*SCALE_LOG2);
        }
    }

    f32x4 o[2][4];
#pragma unroll
    for (int qs = 0; qs < 2; ++qs)
#pragma unroll
        for (int mt = 0; mt < 4; ++mt) o[qs][mt] = (f32x4){0.f, 0.f, 0.f, 0.f};
    f32x4 osum[2] = { (f32x4){0.f,0.f,0.f,0.f}, (f32x4){0.f,0.f,0.f,0.f} };
    const bf16x8 ones8 = { (__bf16)1.0f, (__bf16)1.0f, (__bf16)1.0f, (__bf16)1.0f,
                           (__bf16)1.0f, (__bf16)1.0f, (__bf16)1.0f, (__bf16)1.0f };
    const f32x4 z4 = (f32x4){0.f, 0.f, 0.f, 0.f};   // persistent MFMA C-init

    const char* ibase = img + (size_t)bh * (NT_TILES * (size_t)IMG_BYTES);
    // per-wave mask base: rows qw.., kh pre-split; per tile advance is a uniform offset
    const unsigned* nb_base = nbt + (size_t)kh * 2048 + qw;

    // ---- loop-invariant LDS read offsets (hoisted once)
    int koffs[2][2];
#pragma unroll
    for (int ntl = 0; ntl < 2; ++ntl) {
        const int row = (2 * kh + ntl) * 16 + ln;
        const int rb = row * 128 + ((g ^ (ln & 7)) << 4);
        koffs[ntl][0] = rb; koffs[ntl][1] = rb ^ 64;
    }
    int voffs[4];
#pragma unroll
    for (int mt = 0; mt < 4; ++mt)
        voffs[mt] = (mt * 16 + ln) * 128 + ((((g << 1) | kh) ^ (ln & 7)) << 4);

    char* buf0 = smem;
    char* buf1 = smem + 16384;

    auto stage = [&](int tile, char* dstbase) {
        const char* src = ibase + (size_t)tile * IMG_BYTES + wave * 2048 + lane * 16;
        char* dst = dstbase + wave * 2048;
        gload16(src, dst, lane);
        gload16(src + 1024, dst + 1024, lane);
    };

    auto compute_tile = [&](const char* KB, const char* VB, unsigned nw0, unsigned nw1) {
        // nw0/nw1: pre-inverted keep words for rows qw+ln / qw+16+ln, this kh half
        const unsigned nbs0 = nw0 >> g4;
        const unsigned nbs1 = nw1 >> g4;

        // batch the 4 K b128 reads up front
        bf16x8 ka[2][2];
#pragma unroll
        for (int ntl = 0; ntl < 2; ++ntl) {
            ka[ntl][0] = *(const bf16x8*)(KB + koffs[ntl][0]);
            ka[ntl][1] = *(const bf16x8*)(KB + koffs[ntl][1]);
        }

        // ---- S^T = K.Q^T; exp2 + mask -> merged P frags (key perm: j<4 grp0, j>=4 grp1)
        bf16x8 pa8[2];
#pragma unroll
        for (int ntl = 0; ntl < 2; ++ntl) {
#pragma unroll
            for (int qs = 0; qs < 2; ++qs) {
                __builtin_amdgcn_s_setprio(1);
                f32x4 c = mfma32(ka[ntl][0], qf[qs][0], z4);
                c = mfma32(ka[ntl][1], qf[qs][1], c);
                __builtin_amdgcn_s_setprio(0);
                const unsigned nbs = qs ? nbs1 : nbs0;
#pragma unroll
                for (int r = 0; r < 4; ++r) {
                    const float e = fast_exp2(c[r]);
                    const int keep = (int)(nbs << (31 - (ntl * 16 + r))) >> 31;
                    const float p = __builtin_bit_cast(float,
                        __builtin_bit_cast(unsigned, e) & (unsigned)keep);
                    pa8[qs][ntl * 4 + r] = (__bf16)p;
                }
            }
        }

        // ---- row-sum + PV, batched V reads then pure-MFMA cluster under setprio
        bf16x8 vv[4];
#pragma unroll
        for (int mt = 0; mt < 4; ++mt) vv[mt] = *(const bf16x8*)(VB + voffs[mt]);
        __builtin_amdgcn_s_setprio(1);
#pragma unroll
        for (int qs = 0; qs < 2; ++qs) osum[qs] = mfma32(pa8[qs], ones8, osum[qs]);
#pragma unroll
        for (int mt = 0; mt < 4; ++mt)
#pragma unroll
            for (int qs = 0; qs < 2; ++qs)
                o[qs][mt] = mfma32(pa8[qs], vv[mt], o[qs][mt]);
        __builtin_amdgcn_s_setprio(0);
    };

    // prologue: tile 0 -> buf0 (8 waves x 2KB each)
    stage(0, buf0);
    unsigned mwA0 = nb_base[ln], mwA1 = nb_base[16 + ln];
    __syncthreads();

#pragma unroll 1
    for (int i = 0; i < NT_TILES / 2; ++i) {
        const int t = 2 * i;
        // half A: consume buf0 (tile t), prefetch tile t+1 -> buf1
        stage(t + 1, buf1);
        const unsigned* pB = nb_base + (size_t)(t + 1) * 4096;
        const unsigned mwB0 = pB[ln], mwB1 = pB[16 + ln];
        compute_tile(buf0, buf0 + 8192, mwA0, mwA1);
        __syncthreads();
        // half B: consume buf1 (tile t+1), prefetch tile t+2 -> buf0
        if (i < NT_TILES / 2 - 1) {
            stage(t + 2, buf0);
            const unsigned* pA = nb_base + (size_t)(t + 2) * 4096;
            mwA0 = pA[ln]; mwA1 = pA[16 + ln];
        }
        compute_tile(buf1, buf1 + 8192, mwB0, mwB1);
        __syncthreads();
    }

    // ---- epilogue: two 64-row passes; kh halves combined through LDS
#pragma unroll
    for (int pass = 0; pass < 2; ++pass) {
        if ((qp >> 1) == pass) {
            const int qpl = qp & 1;
#pragma unroll
            for (int qs = 0; qs < 2; ++qs) {
#pragma unroll
                for (int mt = 0; mt < 4; ++mt)
#pragma unroll
                    for (int r = 0; r < 4; ++r)
                        Ep[(size_t)kh * 4096 + (qpl * 32 + qs * 16 + g * 4 + r) * 64 + mt * 16 + ln] = o[qs][mt][r];
                if (ln == 0) {
#pragma unroll
                    for (int r = 0; r < 4; ++r)
                        Os[kh * 64 + qpl * 32 + qs * 16 + g * 4 + r] = osum[qs][r];
                }
            }
        }
        __syncthreads();
        // cooperative, coalesced output: 64 rows x 64 d fp32 (512 threads -> 2 quads each)
#pragma unroll
        for (int p2 = 0; p2 < 2; ++p2) {
            const int idx = p2 * 512 + tid;
            const int row = idx >> 4, c4 = (idx & 15) * 4;
            const float sl = Os[row] + Os[64 + row];
            const float inv = (sl > 0.f) ? (1.f / sl) : 0.f;
            const float4 a  = *(const float4*)(Ep + row * 64 + c4);
            const float4 b4 = *(const float4*)(Ep + 4096 + row * 64 + c4);
            const float4 st = { (a.x + b4.x) * inv, (a.y + b4.y) * inv,
                                (a.z + b4.z) * inv, (a.w + b4.w) * inv };
            *(float4*)(out + ((size_t)bh * T_SEQ + qt * 128 + pass * 64 + row) * D_HEAD + c4) = st;
        }
        if (pass == 0) __syncthreads();   // Ep/Os reused by pass 1
    }
}

extern "C" void kernel_launch(void* const* d_in, const int* in_sizes, int n_in,
                              void* d_out, int out_size, void* d_ws, size_t ws_size,
                              hipStream_t stream) {
    const float* q    = (const float*)d_in[0];
    const float* k    = (const float*)d_in[1];
    const float* v    = (const float*)d_in[2];
    const int*   mask = (const int*)d_in[3];
    float*       out  = (float*)d_out;

    char* img = (char*)d_ws + WS_IMG;
    unsigned* nbt = (unsigned*)((char*)d_ws + WS_MB);

    prep_kv<<<dim3(NT_TILES, BH_N), 256, 0, stream>>>(k, v, img);
    mpack<<<(T_SEQ * T_SEQ) / 256, 256, 0, stream>>>(mask, nbt);
    attn15<<<dim3(QT_N * BH_N), 512, 0, stream>>>(q, img, nbt, out);
}

// Round 9
// 153.376 us; speedup vs baseline: 1.0836x; 1.0145x over previous
//
#include <hip/hip_runtime.h>
#include <hip/hip_bf16.h>

typedef __bf16 bf16x8 __attribute__((ext_vector_type(8)));
typedef __bf16 bf16x4 __attribute__((ext_vector_type(4)));
typedef float  f32x4  __attribute__((ext_vector_type(4)));

#define T_SEQ 2048
#define D_HEAD 64
#define BH_N 32
#define NT_TILES (T_SEQ / 64)        // 32
#define QT_N 16                      // 128 q-rows per block
#define IMG_BYTES 16384              // per-(bh,kt) tile image: 8KB K + 8KB V
#define SCALE_LOG2 0.18033688011112042f   // 0.125 * log2(e)

#define WS_IMG ((size_t)0)
#define WS_MB  ((size_t)16u << 20)

static __device__ __forceinline__ f32x4 mfma32(bf16x8 a, bf16x8 b, f32x4 c) {
    return __builtin_amdgcn_mfma_f32_16x16x32_bf16(a, b, c, 0, 0, 0);
}

static __device__ __forceinline__ float fast_exp2(float x) {
#if __has_builtin(__builtin_amdgcn_exp2f)
    return __builtin_amdgcn_exp2f(x);   // raw v_exp_f32; inputs bounded, no fixup needed
#else
    return exp2f(x);
#endif
}

static __device__ __forceinline__ int sext_bit(unsigned w, int idx) {
#if __has_builtin(__builtin_amdgcn_sbfe)
    return __builtin_amdgcn_sbfe((int)w, idx, 1);      // v_bfe_i32: 1 instr
#else
    return (int)(w << (31 - idx)) >> 31;
#endif
}

// async global->LDS, 16B per lane. LDS dest is wave-uniform base + lane*16 (HW rule);
// the swizzle lives in the GLOBAL image layout, LDS stays linear.
static __device__ __forceinline__ void gload16(const void* g, void* l, int lane) {
#if __has_builtin(__builtin_amdgcn_global_load_lds)
    (void)lane;
    __builtin_amdgcn_global_load_lds(
        (const __attribute__((address_space(1))) void*)g,
        (__attribute__((address_space(3))) void*)l, 16, 0, 0);
#else
    *((f32x4*)l + lane) = *(const f32x4*)g;
#endif
}

// ---------------- prepass: build per-tile LDS images ----------------
// Image for (bh,kt), 16KB:
//   K half (8KB): row kr (key 0..63) x 128B; 16B chunk m = K[key][d-chunk m^(kr&7)]
//   V half (8KB): row r  (d   0..63) x 128B; 16B chunk m: u=m^(r&7), kh=u&1, g=u>>1,
//       bytes0-7 = V[32kh+4g+{0..3}][d=r], bytes8-15 = V[32kh+16+4g+{0..3}][d=r]

__global__ __launch_bounds__(256) void prep_kv(const float* __restrict__ k,
                                               const float* __restrict__ v,
                                               char* __restrict__ img) {
    __shared__ __bf16 t[64][72];
    const int bh = blockIdx.y, tt = blockIdx.x, tid = threadIdx.x;
    char* ob = img + ((size_t)bh * NT_TILES + tt) * IMG_BYTES;
    {
        const int kr = tid >> 2, qd = tid & 3, ke = kr & 7;
        const size_t base = ((size_t)bh * T_SEQ + tt * 64 + kr) * D_HEAD + qd * 16;
        const float4 a0 = *(const float4*)(k + base);
        const float4 a1 = *(const float4*)(k + base + 4);
        const float4 a2 = *(const float4*)(k + base + 8);
        const float4 a3 = *(const float4*)(k + base + 12);
        bf16x8 w0, w1;
        w0[0]=(__bf16)a0.x; w0[1]=(__bf16)a0.y; w0[2]=(__bf16)a0.z; w0[3]=(__bf16)a0.w;
        w0[4]=(__bf16)a1.x; w0[5]=(__bf16)a1.y; w0[6]=(__bf16)a1.z; w0[7]=(__bf16)a1.w;
        w1[0]=(__bf16)a2.x; w1[1]=(__bf16)a2.y; w1[2]=(__bf16)a2.z; w1[3]=(__bf16)a2.w;
        w1[4]=(__bf16)a3.x; w1[5]=(__bf16)a3.y; w1[6]=(__bf16)a3.z; w1[7]=(__bf16)a3.w;
        *(bf16x8*)(ob + kr * 128 + (((2 * qd + 0) ^ ke) << 4)) = w0;
        *(bf16x8*)(ob + kr * 128 + (((2 * qd + 1) ^ ke) << 4)) = w1;
    }
    {
        const int tr = tid >> 4, c4 = (tid & 15) * 4;
        const float* src = v + ((size_t)bh * T_SEQ + tt * 64) * D_HEAD;
#pragma unroll
        for (int p = 0; p < 4; ++p) {
            const int row = p * 16 + tr;
            const float4 f = *(const float4*)(src + row * D_HEAD + c4);
            t[c4+0][row] = (__bf16)f.x; t[c4+1][row] = (__bf16)f.y;
            t[c4+2][row] = (__bf16)f.z; t[c4+3][row] = (__bf16)f.w;
        }
        __syncthreads();
        const int d = tid >> 2;
        char* vb = ob + 8192 + d * 128;
#pragma unroll
        for (int mi = 0; mi < 2; ++mi) {
            const int m  = (tid & 3) * 2 + mi;
            const int u  = m ^ (d & 7);
            const int k0 = (u & 1) * 32 + (u >> 1) * 4;
            const bf16x4 lo = *(const bf16x4*)&t[d][k0];
            const bf16x4 hi = *(const bf16x4*)&t[d][k0 + 16];
            *(bf16x8*)(vb + m * 16) = __builtin_shufflevector(lo, hi, 0,1,2,3,4,5,6,7);
        }
    }
}

// mask prepass: transposed + pre-inverted + kh-pre-split keep-bit words.
// nbt[(t*2 + kh)*2048 + row] = ~bits(mask[row][t*64 + kh*32 .. +31])
__global__ void mpack(const int* __restrict__ m, unsigned* __restrict__ nbt) {
    const int i = blockIdx.x * 256 + threadIdx.x;
    const unsigned long long b = __ballot(m[i] != 0);
    if ((threadIdx.x & 63) == 0) {
        const int wi  = i >> 6;          // word index = row*32 + t
        const int row = wi >> 5;
        const int t   = wi & 31;
        nbt[(size_t)(t * 2 + 0) * 2048 + row] = ~(unsigned)b;
        nbt[(size_t)(t * 2 + 1) * 2048 + row] = ~(unsigned)(b >> 32);
    }
}

// ---------------- main kernel ----------------
// attn16 = attn15 + 4-buffer LDS rotation with a barrier every 2 tiles (was 2 buffers /
// barrier every tile). Grid 512 = 2 blocks/CU, so each block can use 66KB LDS (2x66 <=
// 160K). Effect: barrier count halves (32 -> 16) and waves get a 2-tile drift window
// between barriers -> phase diversity (one wave's exp2/VALU overlaps another's LDS
// reads) instead of all-8-wave lockstep phase collisions. Even-numbered stages get 2
// full tiles of in-flight slack. compute_tile / image layout / mask path identical to
// verified attn15; keep-bit now via v_bfe_i32 (2 VALU/score instead of 3).

__global__ __launch_bounds__(512, 4) void attn16(
    const float* __restrict__ q, const char* __restrict__ img,
    const unsigned* __restrict__ nbt, float* __restrict__ out)
{
    // XCD swizzle: linear block id -> (bh, qt) s.t. XCD x hosts bh in [4x, 4x+4), all qt.
    const int l   = blockIdx.x;          // 0..511
    const int m_  = l >> 3;              // 0..63
    const int bh  = ((l & 7) << 2) | (m_ & 3);
    const int qt  = m_ >> 2;             // 0..15 (128 q rows each)

    const int tid = threadIdx.x, wave = tid >> 6, lane = tid & 63;
    const int g = lane >> 4, ln = lane & 15;
    const int qp = wave & 3, kh = wave >> 2;
    const int g4 = g * 4;

    __shared__ __align__(16) char smem[66048];
    float* Ep = (float*)smem;                // epilogue overlay: [2][64][64] f32 (b0+b1)
    float* Os = (float*)(smem + 65536);      // row sums [2][64]

    const int qw = qt * 128 + qp * 32;

    // ---- Q B-frags (log2-scaled): lane n=ln holds Q[qw+qs*16+ln][kc*32+g*8+j]
    bf16x8 qf[2][2];
#pragma unroll
    for (int qs = 0; qs < 2; ++qs) {
        const float* qpt = q + ((size_t)bh * T_SEQ + qw + qs * 16 + ln) * D_HEAD + g * 8;
#pragma unroll
        for (int kc = 0; kc < 2; ++kc) {
            const float4 f0 = *(const float4*)(qpt + kc * 32);
            const float4 f1 = *(const float4*)(qpt + kc * 32 + 4);
            qf[qs][kc][0]=(__bf16)(f0.x*SCALE_LOG2); qf[qs][kc][1]=(__bf16)(f0.y*SCALE_LOG2);
            qf[qs][kc][2]=(__bf16)(f0.z*SCALE_LOG2); qf[qs][kc][3]=(__bf16)(f0.w*SCALE_LOG2);
            qf[qs][kc][4]=(__bf16)(f1.x*SCALE_LOG2); qf[qs][kc][5]=(__bf16)(f1.y*SCALE_LOG2);
            qf[qs][kc][6]=(__bf16)(f1.z*SCALE_LOG2); qf[qs][kc][7]=(__bf16)(f1.w*SCALE_LOG2);
        }
    }

    f32x4 o[2][4];
#pragma unroll
    for (int qs = 0; qs < 2; ++qs)
#pragma unroll
        for (int mt = 0; mt < 4; ++mt) o[qs][mt] = (f32x4){0.f, 0.f, 0.f, 0.f};
    f32x4 osum[2] = { (f32x4){0.f,0.f,0.f,0.f}, (f32x4){0.f,0.f,0.f,0.f} };
    const bf16x8 ones8 = { (__bf16)1.0f, (__bf16)1.0f, (__bf16)1.0f, (__bf16)1.0f,
                           (__bf16)1.0f, (__bf16)1.0f, (__bf16)1.0f, (__bf16)1.0f };
    const f32x4 z4 = (f32x4){0.f, 0.f, 0.f, 0.f};   // persistent MFMA C-init

    const char* ibase = img + (size_t)bh * (NT_TILES * (size_t)IMG_BYTES);
    const unsigned* nb_base = nbt + (size_t)kh * 2048 + qw;

    // ---- loop-invariant LDS read offsets (hoisted once)
    int koffs[2][2];
#pragma unroll
    for (int ntl = 0; ntl < 2; ++ntl) {
        const int row = (2 * kh + ntl) * 16 + ln;
        const int rb = row * 128 + ((g ^ (ln & 7)) << 4);
        koffs[ntl][0] = rb; koffs[ntl][1] = rb ^ 64;
    }
    int voffs[4];
#pragma unroll
    for (int mt = 0; mt < 4; ++mt)
        voffs[mt] = (mt * 16 + ln) * 128 + ((((g << 1) | kh) ^ (ln & 7)) << 4);

    char* const b0 = smem;
    char* const b1 = smem + 16384;
    char* const b2 = smem + 32768;
    char* const b3 = smem + 49152;

    auto stage = [&](int tile, char* dstbase) {
        const char* src = ibase + (size_t)tile * IMG_BYTES + wave * 2048 + lane * 16;
        char* dst = dstbase + wave * 2048;
        gload16(src, dst, lane);
        gload16(src + 1024, dst + 1024, lane);
    };

    auto compute_tile = [&](const char* KB, unsigned nw0, unsigned nw1) {
        const char* VB = KB + 8192;
        const unsigned nbs0 = nw0 >> g4;
        const unsigned nbs1 = nw1 >> g4;

        // batch the 4 K b128 reads up front
        bf16x8 ka[2][2];
#pragma unroll
        for (int ntl = 0; ntl < 2; ++ntl) {
            ka[ntl][0] = *(const bf16x8*)(KB + koffs[ntl][0]);
            ka[ntl][1] = *(const bf16x8*)(KB + koffs[ntl][1]);
        }

        // ---- S^T = K.Q^T; exp2 + mask -> merged P frags (key perm: j<4 grp0, j>=4 grp1)
        bf16x8 pa8[2];
#pragma unroll
        for (int ntl = 0; ntl < 2; ++ntl) {
#pragma unroll
            for (int qs = 0; qs < 2; ++qs) {
                __builtin_amdgcn_s_setprio(1);
                f32x4 c = mfma32(ka[ntl][0], qf[qs][0], z4);
                c = mfma32(ka[ntl][1], qf[qs][1], c);
                __builtin_amdgcn_s_setprio(0);
                const unsigned nbs = qs ? nbs1 : nbs0;
#pragma unroll
                for (int r = 0; r < 4; ++r) {
                    const float e = fast_exp2(c[r]);
                    const int keep = sext_bit(nbs, ntl * 16 + r);
                    const float p = __builtin_bit_cast(float,
                        __builtin_bit_cast(unsigned, e) & (unsigned)keep);
                    pa8[qs][ntl * 4 + r] = (__bf16)p;
                }
            }
        }

        // ---- row-sum + PV, batched V reads then pure-MFMA cluster under setprio
        bf16x8 vv[4];
#pragma unroll
        for (int mt = 0; mt < 4; ++mt) vv[mt] = *(const bf16x8*)(VB + voffs[mt]);
        __builtin_amdgcn_s_setprio(1);
#pragma unroll
        for (int qs = 0; qs < 2; ++qs) osum[qs] = mfma32(pa8[qs], ones8, osum[qs]);
#pragma unroll
        for (int mt = 0; mt < 4; ++mt)
#pragma unroll
            for (int qs = 0; qs < 2; ++qs)
                o[qs][mt] = mfma32(pa8[qs], vv[mt], o[qs][mt]);
        __builtin_amdgcn_s_setprio(0);
    };

    unsigned mwA0, mwA1, mwB0, mwB1;

    // prologue: tiles 0,1 -> b0,b1; masks for tile 0
    stage(0, b0);
    stage(1, b1);
    mwA0 = nb_base[ln]; mwA1 = nb_base[16 + ln];
    __syncthreads();

    // main: 7 groups x 4 tiles (t = 0..27), barrier every 2 tiles
#pragma unroll 1
    for (int i = 0; i < 7; ++i) {
        const int t = 4 * i;
        {   // slot t: read b0, stage t+2 -> b2
            stage(t + 2, b2);
            const unsigned* p = nb_base + (size_t)(t + 1) * 4096;
            mwB0 = p[ln]; mwB1 = p[16 + ln];
            compute_tile(b0, mwA0, mwA1);
        }
        {   // slot t+1: read b1, stage t+3 -> b3
            stage(t + 3, b3);
            const unsigned* p = nb_base + (size_t)(t + 2) * 4096;
            mwA0 = p[ln]; mwA1 = p[16 + ln];
            compute_tile(b1, mwB0, mwB1);
        }
        __syncthreads();
        {   // slot t+2: read b2, stage t+4 -> b0
            stage(t + 4, b0);
            const unsigned* p = nb_base + (size_t)(t + 3) * 4096;
            mwB0 = p[ln]; mwB1 = p[16 + ln];
            compute_tile(b2, mwA0, mwA1);
        }
        {   // slot t+3: read b3, stage t+5 -> b1
            stage(t + 5, b1);
            const unsigned* p = nb_base + (size_t)(t + 4) * 4096;
            mwA0 = p[ln]; mwA1 = p[16 + ln];
            compute_tile(b3, mwB0, mwB1);
        }
        __syncthreads();
    }

    // tail: tiles 28..31 (stages 30,31 only)
    {   // t=28: read b0, stage 30 -> b2
        stage(30, b2);
        const unsigned* p = nb_base + (size_t)29 * 4096;
        mwB0 = p[ln]; mwB1 = p[16 + ln];
        compute_tile(b0, mwA0, mwA1);
    }
    {   // t=29: read b1, stage 31 -> b3
        stage(31, b3);
        const unsigned* p = nb_base + (size_t)30 * 4096;
        mwA0 = p[ln]; mwA1 = p[16 + ln];
        compute_tile(b1, mwB0, mwB1);
    }
    __syncthreads();
    {   // t=30: read b2
        const unsigned* p = nb_base + (size_t)31 * 4096;
        mwB0 = p[ln]; mwB1 = p[16 + ln];
        compute_tile(b2, mwA0, mwA1);
    }
    {   // t=31: read b3
        compute_tile(b3, mwB0, mwB1);
    }

    // ---- epilogue: two 64-row passes; kh halves combined through LDS.
    // Ep overlays b0/b1 only; all b0/b1 reads finished before the last barrier, and
    // concurrent b2/b3 readers are disjoint from the Ep region.
#pragma unroll
    for (int pass = 0; pass < 2; ++pass) {
        if ((qp >> 1) == pass) {
            const int qpl = qp & 1;
#pragma unroll
            for (int qs = 0; qs < 2; ++qs) {
#pragma unroll
                for (int mt = 0; mt < 4; ++mt)
#pragma unroll
                    for (int r = 0; r < 4; ++r)
                        Ep[(size_t)kh * 4096 + (qpl * 32 + qs * 16 + g * 4 + r) * 64 + mt * 16 + ln] = o[qs][mt][r];
                if (ln == 0) {
#pragma unroll
                    for (int r = 0; r < 4; ++r)
                        Os[kh * 64 + qpl * 32 + qs * 16 + g * 4 + r] = osum[qs][r];
                }
            }
        }
        __syncthreads();
        // cooperative, coalesced output: 64 rows x 64 d fp32 (512 threads -> 2 quads each)
#pragma unroll
        for (int p2 = 0; p2 < 2; ++p2) {
            const int idx = p2 * 512 + tid;
            const int row = idx >> 4, c4 = (idx & 15) * 4;
            const float sl = Os[row] + Os[64 + row];
            const float inv = (sl > 0.f) ? (1.f / sl) : 0.f;
            const float4 a  = *(const float4*)(Ep + row * 64 + c4);
            const float4 b4 = *(const float4*)(Ep + 4096 + row * 64 + c4);
            const float4 st = { (a.x + b4.x) * inv, (a.y + b4.y) * inv,
                                (a.z + b4.z) * inv, (a.w + b4.w) * inv };
            *(float4*)(out + ((size_t)bh * T_SEQ + qt * 128 + pass * 64 + row) * D_HEAD + c4) = st;
        }
        if (pass == 0) __syncthreads();   // Ep/Os reused by pass 1
    }
}

extern "C" void kernel_launch(void* const* d_in, const int* in_sizes, int n_in,
                              void* d_out, int out_size, void* d_ws, size_t ws_size,
                              hipStream_t stream) {
    const float* q    = (const float*)d_in[0];
    const float* k    = (const float*)d_in[1];
    const float* v    = (const float*)d_in[2];
    const int*   mask = (const int*)d_in[3];
    float*       out  = (float*)d_out;

    char* img = (char*)d_ws + WS_IMG;
    unsigned* nbt = (unsigned*)((char*)d_ws + WS_MB);

    prep_kv<<<dim3(NT_TILES, BH_N), 256, 0, stream>>>(k, v, img);
    mpack<<<(T_SEQ * T_SEQ) / 256, 256, 0, stream>>>(mask, nbt);
    attn16<<<dim3(QT_N * BH_N), 512, 0, stream>>>(q, img, nbt, out);
}